// Round 13
// baseline (5635.496 us; speedup 1.0000x reference)
//
#include <hip/hip_runtime.h>
#include <hip/hip_bf16.h>

#define K_ITERS 20
#define F_IN 512
#define F_HID 128
#define F_OUT 40
#define NSLAB 5

// Dataset is FP32 end-to-end (established round 3/6). Output buffer fp32 (16 MB).
// R12 fix: R10's k_prop meta-prefetch read `pair[beg+(c+1)*8+e8]` behind an
// uninitialized-on-last-iter variable (UB). If the compiler hoists the load
// unconditionally, the last row of the last node reads past pair[EP) -> GPU
// aperture fault -> the observed core dump. Fixed with an always-in-bounds
// clamped prefetch index (pn = min(c+1, nch-1)). Design otherwise identical:
// FEATURE-SLICED PROPAGATION. R9 proved gather cost is per-LINE -> k_prop at
// L3 random-line roofline (~700MB/iter @ ~6TB/s). Slice 40 feats into 5 slabs
// of 8 (slab z = N*32B = 3.2MB < 4MB per-XCD L2, read-only -> each XCD caches
// it whole). One launch/iter, slab-major block order. Wave-per-node,
// lane=(edge-slot, feat), 8-edge chunks (pad8, self-loop folded, int2 meta;
// memset-0 padding = src 0 / norm 0.0 exact). Gather = aligned 32B row,
// 1 line/edge, from L2 @34.5TB/s instead of L3. h0 slab-major (doubles as z0).
// k_mlp = R9 (252us) except h0s write layout.

typedef const float __attribute__((address_space(1)))* glb_fp;
typedef float __attribute__((address_space(3)))* lds_fp;

// ---------- in-degree histogram over col (targets) ----------
__global__ void k_hist(const int* __restrict__ col, int E, int* __restrict__ cnt){
  int e = blockIdx.x*blockDim.x + threadIdx.x;
  if (e < E) atomicAdd(&cnt[col[e]], 1);
}

// ---------- dinv = rsqrt(in_deg + 1) ----------
__global__ void k_dinv(const int* __restrict__ cnt, int N, float* __restrict__ dinv){
  int i = blockIdx.x*blockDim.x + threadIdx.x;
  if (i < N) dinv[i] = rsqrtf((float)(cnt[i] + 1));
}

// ---------- scans over padded counts: pad8(cnt[i]+1 self) ----------
__device__ __forceinline__ int pad8(int c){ return (c + 8) & ~7; }  // pad8(cnt+1)

__global__ void k_scan1(const int* __restrict__ cnt, int N, int* __restrict__ bsum){
  __shared__ int sd[256];
  int base = blockIdx.x*2048 + threadIdx.x*8;
  int t = threadIdx.x;
  int s = 0;
  #pragma unroll
  for (int j=0;j<8;++j){ int i=base+j; if (i<N) s += pad8(cnt[i]); }
  sd[t] = s; __syncthreads();
  for (int off=1; off<256; off<<=1){
    int v = (t>=off)? sd[t-off] : 0;
    __syncthreads();
    sd[t] += v;
    __syncthreads();
  }
  if (t==255) bsum[blockIdx.x] = sd[255];
}
__global__ void k_scan2(const int* __restrict__ bsum, int NB, int* __restrict__ boff,
                        int* __restrict__ rp, int N){
  __shared__ int sd[256];
  int t = threadIdx.x;
  int v = (t < NB) ? bsum[t] : 0;
  sd[t] = v; __syncthreads();
  for (int off=1; off<256; off<<=1){
    int u = (t>=off)? sd[t-off] : 0;
    __syncthreads();
    sd[t] += u;
    __syncthreads();
  }
  if (t < NB) boff[t] = sd[t] - v;
  if (t == NB-1) rp[N] = sd[t];
}
__global__ void k_scan3(const int* __restrict__ cnt, int N, const int* __restrict__ boff,
                        int* __restrict__ rp){
  __shared__ int sd[256];
  int base = blockIdx.x*2048 + threadIdx.x*8;
  int t = threadIdx.x;
  int c[8]; int s = 0;
  #pragma unroll
  for (int j=0;j<8;++j){ int i=base+j; c[j] = (i<N)? pad8(cnt[i]) : 0; s += c[j]; }
  sd[t] = s; __syncthreads();
  for (int off=1; off<256; off<<=1){
    int v = (t>=off)? sd[t-off] : 0;
    __syncthreads();
    sd[t] += v;
    __syncthreads();
  }
  int run = sd[t] - s + boff[blockIdx.x];
  #pragma unroll
  for (int j=0;j<8;++j){ int i=base+j; if (i<N) rp[i] = run; run += c[j]; }
}

// ---------- scatter edges into padded CSR of (src, norm) pairs ----------
__global__ void k_scatter(const int* __restrict__ row, const int* __restrict__ col, int E,
                          const int* __restrict__ rp, int* __restrict__ cur,
                          const float* __restrict__ dinv, int2* __restrict__ pair){
  int e = blockIdx.x*blockDim.x + threadIdx.x;
  if (e >= E) return;
  int r = row[e], c = col[e];
  int p = rp[c] + atomicAdd(&cur[c], 1);
  pair[p] = make_int2(r, __float_as_int(dinv[r]*dinv[c]));
}
// ---------- self-loop entries (norm = dinv^2) ----------
__global__ void k_selfpair(int N, const int* __restrict__ rp, int* __restrict__ cur,
                           const float* __restrict__ dinv, int2* __restrict__ pair){
  int n = blockIdx.x*blockDim.x + threadIdx.x;
  if (n >= N) return;
  int p = rp[n] + atomicAdd(&cur[n], 1);
  float di = dinv[n];
  pair[p] = make_int2(n, __float_as_int(di*di));
}

// ---------- fused MLP: x AND W1 staged via coalesced global_load_lds ----------
// Same as R9 (252us) except h0 is written SLAB-MAJOR: h0s[(c>>3)*N + n][c&7].
__global__ __launch_bounds__(256) void k_mlp(const float* __restrict__ x,
                      const float* __restrict__ W1, const float* __restrict__ b1,
                      const float* __restrict__ W2, const float* __restrict__ b2,
                      float* __restrict__ h0s, int N){
  __shared__ float lds[12288];       // 48KB
  const int t    = threadIdx.x;
  const int th   = t & 31;
  const int tn   = t >> 5;
  const int lane = t & 63;
  const int wv   = __builtin_amdgcn_readfirstlane(t >> 6);   // 0..3
  const int nb   = blockIdx.x * 64;

  auto stage_w = [&](int kt, int b){
    const float* gs = W1 + kt*(32*128) + wv*1024 + lane*4;
    int lo = __builtin_amdgcn_readfirstlane((b*4096 + wv*1024) * 4); // bytes
    #pragma unroll
    for (int i=0;i<4;++i){
      __builtin_amdgcn_global_load_lds((glb_fp)(gs + i*256),
        (lds_fp)((char*)lds + lo + i*1024), 16, 0, 0);
    }
  };
  auto stage_x = [&](int kt, int b){
    #pragma unroll
    for (int s=0;s<2;++s){
      int i = wv*2 + s;                 // 0..7
      int flat = i*256 + lane*4;        // float index in [64][32]
      int n = flat >> 5;
      int kk = flat & 31;
      int node = nb + n; if (node >= N) node = N-1;
      const float* gs = x + (size_t)node*F_IN + kt*32 + kk;
      int lo = __builtin_amdgcn_readfirstlane(32768 + b*8192 + i*1024); // bytes
      __builtin_amdgcn_global_load_lds((glb_fp)gs,
        (lds_fp)((char*)lds + lo), 16, 0, 0);
    }
  };

  float acc[8][4];
  {
    float4 bb = *(const float4*)(b1 + th*4);
    #pragma unroll
    for (int j=0;j<8;++j){ acc[j][0]=bb.x; acc[j][1]=bb.y; acc[j][2]=bb.z; acc[j][3]=bb.w; }
  }

  stage_w(0, 0); stage_x(0, 0);
  __syncthreads();

  for (int kt=0; kt<16; ++kt){
    const int cur = kt & 1;
    if (kt < 15){ stage_w(kt+1, cur^1); stage_x(kt+1, cur^1); }
    const float* xb = lds + 8192 + cur*2048;   // [64][32]
    const float* wb = lds + cur*4096;          // [32][128]
    #pragma unroll
    for (int c=0;c<8;++c){
      float4 xv[8];
      #pragma unroll
      for (int j=0;j<8;++j) xv[j] = *(const float4*)(xb + (tn*8+j)*32 + c*4);
      const float* wl = wb + c*512 + th*4;
      float4 wa = *(const float4*)(wl);
      float4 wb4 = *(const float4*)(wl + 128);
      float4 wc = *(const float4*)(wl + 256);
      float4 wd = *(const float4*)(wl + 384);
      #pragma unroll
      for (int j=0;j<8;++j){
        acc[j][0] += xv[j].x*wa.x; acc[j][1] += xv[j].x*wa.y; acc[j][2] += xv[j].x*wa.z; acc[j][3] += xv[j].x*wa.w;
        acc[j][0] += xv[j].y*wb4.x; acc[j][1] += xv[j].y*wb4.y; acc[j][2] += xv[j].y*wb4.z; acc[j][3] += xv[j].y*wb4.w;
        acc[j][0] += xv[j].z*wc.x; acc[j][1] += xv[j].z*wc.y; acc[j][2] += xv[j].z*wc.z; acc[j][3] += xv[j].z*wc.w;
        acc[j][0] += xv[j].w*wd.x; acc[j][1] += xv[j].w*wd.y; acc[j][2] += xv[j].w*wd.z; acc[j][3] += xv[j].w*wd.w;
      }
    }
    __syncthreads();
  }

  // relu + write h1 transposed: h1tT[hid][node], pad 68 (conflict-free reads)
  #pragma unroll
  for (int h=0; h<4; ++h){
    const int hid = th*4 + h;
    float4 v0 = make_float4(fmaxf(acc[0][h],0.f), fmaxf(acc[1][h],0.f),
                            fmaxf(acc[2][h],0.f), fmaxf(acc[3][h],0.f));
    float4 v1 = make_float4(fmaxf(acc[4][h],0.f), fmaxf(acc[5][h],0.f),
                            fmaxf(acc[6][h],0.f), fmaxf(acc[7][h],0.f));
    *(float4*)&lds[hid*68 + tn*8]     = v0;
    *(float4*)&lds[hid*68 + tn*8 + 4] = v1;
  }
  __syncthreads();

  // GEMM2: wave wv owns cols wv*10..+9; lane = node. W2/b2 via uniform s_load.
  const int c0 = wv*10;
  float a2[10];
  #pragma unroll
  for (int i=0;i<10;++i) a2[i] = b2[c0+i];
  #pragma unroll 4
  for (int k=0;k<F_HID;++k){
    const float hv = lds[k*68 + lane];
    #pragma unroll
    for (int i=0;i<10;++i) a2[i] += hv * W2[k*F_OUT + c0 + i];
  }
  const int gn = nb + lane;
  if (gn < N){
    #pragma unroll
    for (int i=0;i<10;++i){
      int c = c0 + i;
      h0s[((size_t)(c>>3)*N + gn)*8 + (c&7)] = fmaxf(a2[i], 0.f);
    }
  }
}

// ---------- propagation: z' = 0.9*(A_hat z) + 0.1*h0, feature-sliced ----------
// One launch per iteration; grid = NSLAB*BPS blocks, slab-major (slab=bid/BPS).
// Wave per node; lane = (edge-slot e8=lane>>3, feat f=lane&7). 8-edge chunks.
// Slab z (3.2MB) is L2-resident per XCD; gather = aligned 32B row, 1 line/edge.
// Meta prefetch uses CLAMPED index (always in-bounds, always initialized).
__global__ __launch_bounds__(256) void k_prop(const int* __restrict__ rp,
                      const int2* __restrict__ pair,
                      const float* __restrict__ zin, const float* __restrict__ h0s,
                      float* __restrict__ zout, float* __restrict__ dout,
                      int N, int BPS, int last){
  const int wv   = __builtin_amdgcn_readfirstlane((int)(threadIdx.x >> 6));
  const int bid  = blockIdx.x;
  const int slab = bid / BPS;                      // 0..4
  const int node = (bid - slab*BPS)*4 + wv;
  const int lane = threadIdx.x & 63;
  const int e8   = lane >> 3;
  const int f    = lane & 7;
  if (node >= N) return;

  const int beg = rp[node];
  const int nch = (rp[node+1] - beg) >> 3;         // rows padded to x8, >=1
  const float* zs = zin + (size_t)slab*N*8;

  float acc = 0.f;
  int2 m = pair[beg + e8];
  for (int c=0; c<nch; ++c){
    const int pn = (c+1 < nch) ? (c+1) : c;        // clamped: in-bounds, no UB
    int2 mn = pair[beg + pn*8 + e8];
    const float nm = __int_as_float(m.y);          // padding: 0.0f, src 0
    const float zv = zs[(size_t)m.x*8 + f];
    acc += nm * zv;
    m = mn;
  }

  // reduce across the 8 edge slots (lanes spaced 8 share feat f)
  acc += __shfl_xor(acc, 8);
  acc += __shfl_xor(acc, 16);
  acc += __shfl_xor(acc, 32);

  if (lane < 8){
    const size_t hi = ((size_t)slab*N + node)*8 + f;
    const float v = 0.9f*acc + 0.1f*h0s[hi];
    if (last) dout[(size_t)node*F_OUT + slab*8 + f] = v;
    else      zout[hi] = v;
  }
}

extern "C" void kernel_launch(void* const* d_in, const int* in_sizes, int n_in,
                              void* d_out, int out_size, void* d_ws, size_t ws_size,
                              hipStream_t stream){
  const float* x  = (const float*)d_in[0];
  const int*   ei = (const int*)d_in[1];
  const float* W1 = (const float*)d_in[2];
  const float* b1 = (const float*)d_in[3];
  const float* W2 = (const float*)d_in[4];
  const float* b2 = (const float*)d_in[5];
  int N = in_sizes[0] / F_IN;
  int E = in_sizes[1] / 2;
  const int* row = ei;       // sources
  const int* col = ei + E;   // targets
  size_t EP = (size_t)E + 8ull*(size_t)N;   // edges + self + pad-to-8 worst case

  char* w = (char*)d_ws;
  auto alloc = [&](size_t bytes)->void*{ void* p = w; w += (bytes + 255) & ~255ull; return p; };
  int*   cnt      = (int*)  alloc((size_t)N*4);
  int*   cur      = (int*)  alloc((size_t)N*4);
  int*   rp       = (int*)  alloc(((size_t)N+1)*4);
  float* dinv     = (float*)alloc((size_t)N*4);
  int NB = (N + 2047)/2048;                 // 49 for N=100000 (<=256)
  int*   bsum     = (int*)  alloc((size_t)NB*4);
  int*   boff     = (int*)  alloc((size_t)NB*4);
  int2*  pair     = (int2*) alloc(EP*8);
  float* h0s      = (float*)alloc((size_t)N*F_OUT*4);   // slab-major [5][N][8]
  float* zA       = (float*)alloc((size_t)N*F_OUT*4);   // slab-major
  float* zB       = (float*)alloc((size_t)N*F_OUT*4);   // slab-major

  (void)hipMemsetAsync(cnt, 0, (size_t)N*4, stream);
  (void)hipMemsetAsync(cur, 0, (size_t)N*4, stream);
  (void)hipMemsetAsync(pair, 0, EP*8, stream);   // dummy: src=0, norm=0.0f

  int ge = (E + 255)/256;
  k_hist    <<<ge, 256, 0, stream>>>(col, E, cnt);
  k_dinv    <<<(N+255)/256, 256, 0, stream>>>(cnt, N, dinv);
  k_scan1   <<<NB, 256, 0, stream>>>(cnt, N, bsum);
  k_scan2   <<<1, 256, 0, stream>>>(bsum, NB, boff, rp, N);
  k_scan3   <<<NB, 256, 0, stream>>>(cnt, N, boff, rp);
  k_scatter <<<ge, 256, 0, stream>>>(row, col, E, rp, cur, dinv, pair);
  k_selfpair<<<(N+255)/256, 256, 0, stream>>>(N, rp, cur, dinv, pair);

  k_mlp<<<(N+63)/64, 256, 0, stream>>>(x, W1, b1, W2, b2, h0s, N);

  int BPS = (N + 3)/4;                      // blocks per slab (wave per node)
  int grid = BPS * NSLAB;
  float* zi = h0s; float* zo = zA;
  for (int it=0; it<K_ITERS; ++it){
    int last = (it == K_ITERS-1) ? 1 : 0;
    k_prop<<<grid, 256, 0, stream>>>(rp, pair, zi, h0s, zo, (float*)d_out, N, BPS, last);
    float* nxt = (it==0) ? zB : zi;
    zi = zo; zo = nxt;
  }
}